// Round 8
// baseline (149.835 us; speedup 1.0000x reference)
//
#include <hip/hip_runtime.h>

typedef short v8s __attribute__((ext_vector_type(8)));
typedef float v4f __attribute__((ext_vector_type(4)));
typedef unsigned v4u __attribute__((ext_vector_type(4)));

#define Wh   1024
#define Hh   512
#define HWh  (Wh * Hh)
#define Wlr  512
#define HWlr (Wlr * 256)
#define ITERS 4           // 4 outer iters x 32 px/wave (N-blocked 2x)
#define NBLK  512         // 512 blocks x 8 waves x 4 iters x 32 px = 524288 px (1 row/block)

// LDS layout (shorts): wfrag[53*512] only (act buffer eliminated — register relay)
//   53 fragments (W0:32, W1:16, W2:4, W3:1), lane-contiguous 16B frags
#define WFRAG_SHORTS (53 * 512)
#define LDS_BYTES    (WFRAG_SHORTS * 2)   // 54272

__device__ __forceinline__ unsigned short f2bf(float f) {
    union { float f; unsigned u; } v; v.f = f;
    unsigned r = v.u + 0x7FFFu + ((v.u >> 16) & 1u);  // RNE (cold paths only)
    return (unsigned short)(r >> 16);
}
// hot-path pack: single-instruction packed f32->bf16 (RNE; dst.lo=a, dst.hi=b)
__device__ __forceinline__ unsigned pk2(float a, float b) {
    unsigned r;
    asm("v_cvt_pk_bf16_f32 %0, %1, %2" : "=v"(r) : "v"(a), "v"(b));
    return r;
}
__device__ __forceinline__ float leaky(float x) { return fmaxf(x, 0.01f * x); }

// register relay: build next layer's B-fragment (K-slot ks*32+q*8+j) from this
// layer's two accumulators for mt=2ks ("e") and mt=2ks+1 ("o").
// K-permuted weights ensure slot (ks,j) <- channel (2ks+(j>>2))*16 + q*4 + (j&3).
__device__ __forceinline__ v8s relay(v4f e, v4f o) {
    v4u w;
    w[0] = pk2(leaky(e[0]), leaky(e[1]));
    w[1] = pk2(leaky(e[2]), leaky(e[3]));
    w[2] = pk2(leaky(o[0]), leaky(o[1]));
    w[3] = pk2(leaky(o[2]), leaky(o[3]));
    return __builtin_bit_cast(v8s, w);
}

// 512-thread blocks, min-waves 2 (VGPR cap 256): the live set spills under any
// tighter bound — verified R1/R2 (1024-thr cap 128 -> 240MB scratch) and R4
// ((512,6) cap ~85 -> VGPR 40 + 59MB scratch). DO NOT TIGHTEN.
__global__ __launch_bounds__(512, 2)
void cmfsm_kernel(const float* __restrict__ lr, const float* __restrict__ hr,
                  const float* __restrict__ w0g, const float* __restrict__ w1g,
                  const float* __restrict__ w2g, const float* __restrict__ w3g,
                  const float* __restrict__ w4g, const float* __restrict__ w5g,
                  const float* __restrict__ t0g, const float* __restrict__ t1g,
                  const float* __restrict__ t2g, const float* __restrict__ fwg,
                  float* __restrict__ out)
{
    extern __shared__ unsigned short smem[];
    unsigned short* wfrag = smem;                    // 53*512 shorts

    const int tid  = threadIdx.x;
    const int lane = tid & 63;
    const int wv   = tid >> 6;    // 0..7
    const int p    = lane & 15;   // MFMA n (pixel)
    const int q    = lane >> 4;   // MFMA k-quad

    // ---- stage weights as A-fragments into LDS, fragment-major ----
    // layer 0: identity K mapping (B built straight from global loads)
    for (int e = tid; e < 32 * 64; e += 512) {
        int f = e >> 6, l = e & 63;
        int mt = f >> 2, ks = f & 3, pp = l & 15, qq = l >> 4;
        const float* src = w0g + (mt * 16 + pp) * 128 + ks * 32 + qq * 8;
        unsigned short* dst = wfrag + f * 512 + l * 8;
#pragma unroll
        for (int j = 0; j < 8; ++j) dst[j] = f2bf(src[j]);
    }
    // layers 1..3: K-permuted so B comes from the register relay.
    // slot (ks, qq, j) <- input channel ks*32 + ((j>>2)<<4) + qq*4 + (j&3)
    for (int e = tid; e < 16 * 64; e += 512) {
        int f = e >> 6, l = e & 63;
        int mt = f >> 2, ks = f & 3, pp = l & 15, qq = l >> 4;
        const float* srcrow = w1g + (mt * 16 + pp) * 128;
        unsigned short* dst = wfrag + (32 + f) * 512 + l * 8;
#pragma unroll
        for (int j = 0; j < 8; ++j)
            dst[j] = f2bf(srcrow[ks * 32 + ((j >> 2) << 4) + qq * 4 + (j & 3)]);
    }
    if (tid < 4 * 64) {
        int f = tid >> 6, l = tid & 63;
        int mt = f >> 1, ks = f & 1, pp = l & 15, qq = l >> 4;
        const float* srcrow = w2g + (mt * 16 + pp) * 64;
        unsigned short* dst = wfrag + (48 + f) * 512 + l * 8;
#pragma unroll
        for (int j = 0; j < 8; ++j)
            dst[j] = f2bf(srcrow[ks * 32 + ((j >> 2) << 4) + qq * 4 + (j & 3)]);
    }
    if (tid < 64) {
        int l = tid;
        int pp = l & 15, qq = l >> 4;
        const float* srcrow = w3g + pp * 32;
        unsigned short* dst = wfrag + 52 * 512 + l * 8;
#pragma unroll
        for (int j = 0; j < 8; ++j)
            dst[j] = f2bf(srcrow[((j >> 2) << 4) + qq * 4 + (j & 3)]);
    }

    // ---- fused linear layers 4+5: w45[r] = sum_j w5[j]*w4[j][4q+r] ----
    float w45[4];
#pragma unroll
    for (int r = 0; r < 4; ++r) {
        float s = 0.f;
#pragma unroll
        for (int j = 0; j < 8; ++j) s += w5g[j] * w4g[j * 16 + q * 4 + r];
        w45[r] = s;
    }

    // ---- weights2: 4 parity values; row parity is block-uniform (y = blockIdx) ----
    float w2e, w2o;   // value for even-x / odd-x pixels of this row
    {
        float tab[4];
#pragma unroll
        for (int yp = 0; yp < 2; ++yp)
#pragma unroll
            for (int xp = 0; xp < 2; ++xp) {
                float i0 = xp ? 1.f : -1.f;
                float i1 = yp ? 1.f : -1.f;
                float i2 = 1.41421356237309505f;
                float h0[3], h1[2];
                for (int o = 0; o < 3; ++o)
                    h0[o] = leaky(t0g[o*3+0]*i0 + t0g[o*3+1]*i1 + t0g[o*3+2]*i2);
                for (int o = 0; o < 2; ++o)
                    h1[o] = leaky(t1g[o*3+0]*h0[0] + t1g[o*3+1]*h0[1] + t1g[o*3+2]*h0[2]);
                tab[yp*2+xp] = t2g[0]*h1[0] + t2g[1]*h1[1];
            }
        const int yp = blockIdx.x & 1;
        w2e = yp ? tab[2] : tab[0];
        w2o = yp ? tab[3] : tab[1];
    }
    const float fa = fabsf(fwg[0]);
    const float fb = fabsf(fwg[1]);

    __syncthreads();   // wfrag ready; everything after is wave-private

    const unsigned short* WL = wfrag + lane * 8;     // A-frag read base

    // ---- per-lane per-channel global pointers: lane (q,p) owns ch = q*8+j ----
    // wave owns 32 px per iter: groups g0 = wv*32+p, g1 = +16 (imm 64B).
    // hr base = row*Wh + wv*32 + p, iter imm +256 floats; lr iter imm +128 floats.
    const float* hrp[8];
    const float* lrp[8];
    {
        const int hbase = blockIdx.x * Wh + wv * 32 + p;
        const int lbase = (blockIdx.x >> 1) * Wlr + wv * 16 + (p >> 1);
#pragma unroll
        for (int j = 0; j < 8; ++j) {
            hrp[j] = hr + (size_t)(q * 8 + j) * HWh  + hbase;
            lrp[j] = lr + (size_t)(q * 8 + j) * HWlr + lbase;
        }
    }

    // hoisted serial-tail A-fragments (layers 2+3, loop-invariant, 20 VGPR)
    const v8s a2w[4] = {
        *(const v8s*)(WL + 48 * 512), *(const v8s*)(WL + 49 * 512),
        *(const v8s*)(WL + 50 * 512), *(const v8s*)(WL + 51 * 512)
    };
    const v8s a3 = *(const v8s*)(WL + 52 * 512);

    // output column base for this wave (q==0 lanes store)
    const int obase = blockIdx.x * Wh + wv * 32 + p;

    // ---- software pipeline: preload iteration 0's staging values (both groups) ----
    float h0[8], l0[8], h1[8], l1[8];
#pragma unroll
    for (int j = 0; j < 8; ++j) {
        h0[j] = hrp[j][0];  h1[j] = hrp[j][16];
        l0[j] = lrp[j][0];  l1[j] = lrp[j][8];
    }

#pragma unroll
    for (int it = 0; it < ITERS; ++it) {
        // ---- layer-0 B fragments in registers, both pixel groups ----
        //   ks0 = lr_up, ks1 = hr, ks2 = lr*hr, ks3 = (lr-hr)^2
        v4u fA0, fA1, fA2, fA3, fB0, fB1, fB2, fB3;
#pragma unroll
        for (int u = 0; u < 4; ++u) {
            {
                float la = l0[2*u], lb = l0[2*u+1], ha = h0[2*u], hb = h0[2*u+1];
                fA0[u] = pk2(la, lb);
                fA1[u] = pk2(ha, hb);
                fA2[u] = pk2(la * ha, lb * hb);
                float d0 = la - ha, d1 = lb - hb;
                fA3[u] = pk2(d0 * d0, d1 * d1);
            }
            {
                float la = l1[2*u], lb = l1[2*u+1], ha = h1[2*u], hb = h1[2*u+1];
                fB0[u] = pk2(la, lb);
                fB1[u] = pk2(ha, hb);
                fB2[u] = pk2(la * ha, lb * hb);
                float d0 = la - ha, d1 = lb - hb;
                fB3[u] = pk2(d0 * d0, d1 * d1);
            }
        }
        v8s bA[4] = { __builtin_bit_cast(v8s, fA0), __builtin_bit_cast(v8s, fA1),
                      __builtin_bit_cast(v8s, fA2), __builtin_bit_cast(v8s, fA3) };
        v8s bB[4] = { __builtin_bit_cast(v8s, fB0), __builtin_bit_cast(v8s, fB1),
                      __builtin_bit_cast(v8s, fB2), __builtin_bit_cast(v8s, fB3) };

        // ---- prefetch next iteration (all-immediate addressing, it static) ----
        if (it + 1 < ITERS) {
            const int ho = (it + 1) * 256;   // hr: +256 floats/iter (imm 1024B steps)
            const int lo = (it + 1) * 128;   // lr: +128 floats/iter (imm 512B steps)
#pragma unroll
            for (int j = 0; j < 8; ++j) {
                h0[j] = hrp[j][ho];      h1[j] = hrp[j][ho + 16];
                l0[j] = lrp[j][lo];      l1[j] = lrp[j][lo + 8];
            }
        }

        // ---- layer 0: 128 -> 128; each A-frag read feeds BOTH groups' MFMAs ----
        v8s c1A[4], c1B[4];
#pragma unroll
        for (int ksp = 0; ksp < 4; ++ksp) {
            v4f ae0 = (v4f){0.f,0.f,0.f,0.f}, ao0 = (v4f){0.f,0.f,0.f,0.f};
            v4f ae1 = (v4f){0.f,0.f,0.f,0.f}, ao1 = (v4f){0.f,0.f,0.f,0.f};
#pragma unroll
            for (int ks = 0; ks < 4; ++ks) {
                v8s we = *(const v8s*)(WL + ((2 * ksp)     * 4 + ks) * 512);
                v8s wo = *(const v8s*)(WL + ((2 * ksp + 1) * 4 + ks) * 512);
                ae0 = __builtin_amdgcn_mfma_f32_16x16x32_bf16(we, bA[ks], ae0, 0, 0, 0);
                ao0 = __builtin_amdgcn_mfma_f32_16x16x32_bf16(wo, bA[ks], ao0, 0, 0, 0);
                ae1 = __builtin_amdgcn_mfma_f32_16x16x32_bf16(we, bB[ks], ae1, 0, 0, 0);
                ao1 = __builtin_amdgcn_mfma_f32_16x16x32_bf16(wo, bB[ks], ao1, 0, 0, 0);
            }
            c1A[ksp] = relay(ae0, ao0);
            c1B[ksp] = relay(ae1, ao1);
        }

        // ---- layer 1: 128 -> 64, shared A-frag reads ----
        v8s c2A[2], c2B[2];
#pragma unroll
        for (int ksp = 0; ksp < 2; ++ksp) {
            v4f ae0 = (v4f){0.f,0.f,0.f,0.f}, ao0 = (v4f){0.f,0.f,0.f,0.f};
            v4f ae1 = (v4f){0.f,0.f,0.f,0.f}, ao1 = (v4f){0.f,0.f,0.f,0.f};
#pragma unroll
            for (int ks = 0; ks < 4; ++ks) {
                v8s we = *(const v8s*)(WL + (32 + (2 * ksp)     * 4 + ks) * 512);
                v8s wo = *(const v8s*)(WL + (32 + (2 * ksp + 1) * 4 + ks) * 512);
                ae0 = __builtin_amdgcn_mfma_f32_16x16x32_bf16(we, c1A[ks], ae0, 0, 0, 0);
                ao0 = __builtin_amdgcn_mfma_f32_16x16x32_bf16(wo, c1A[ks], ao0, 0, 0, 0);
                ae1 = __builtin_amdgcn_mfma_f32_16x16x32_bf16(we, c1B[ks], ae1, 0, 0, 0);
                ao1 = __builtin_amdgcn_mfma_f32_16x16x32_bf16(wo, c1B[ks], ao1, 0, 0, 0);
            }
            c2A[ksp] = relay(ae0, ao0);
            c2B[ksp] = relay(ae1, ao1);
        }

        // ---- layer 2: 64 -> 32 (A-frags in registers) ----
        v8s c3A, c3B;
        {
            v4f ae0 = (v4f){0.f,0.f,0.f,0.f}, ao0 = (v4f){0.f,0.f,0.f,0.f};
            v4f ae1 = (v4f){0.f,0.f,0.f,0.f}, ao1 = (v4f){0.f,0.f,0.f,0.f};
#pragma unroll
            for (int ks = 0; ks < 2; ++ks) {
                ae0 = __builtin_amdgcn_mfma_f32_16x16x32_bf16(a2w[ks],     c2A[ks], ae0, 0, 0, 0);
                ao0 = __builtin_amdgcn_mfma_f32_16x16x32_bf16(a2w[2 + ks], c2A[ks], ao0, 0, 0, 0);
                ae1 = __builtin_amdgcn_mfma_f32_16x16x32_bf16(a2w[ks],     c2B[ks], ae1, 0, 0, 0);
                ao1 = __builtin_amdgcn_mfma_f32_16x16x32_bf16(a2w[2 + ks], c2B[ks], ao1, 0, 0, 0);
            }
            c3A = relay(ae0, ao0);
            c3B = relay(ae1, ao1);
        }

        // ---- layer 3: 32 -> 16, fused 16->8->1, fuse with weights2, both groups ----
        {
            v4f acc3A = __builtin_amdgcn_mfma_f32_16x16x32_bf16(a3, c3A, (v4f){0.f,0.f,0.f,0.f}, 0, 0, 0);
            v4f acc3B = __builtin_amdgcn_mfma_f32_16x16x32_bf16(a3, c3B, (v4f){0.f,0.f,0.f,0.f}, 0, 0, 0);

            float p0 = 0.f, p1 = 0.f;
#pragma unroll
            for (int r = 0; r < 4; ++r) {
                p0 += w45[r] * leaky(acc3A[r]);
                p1 += w45[r] * leaky(acc3B[r]);
            }
            p0 += __shfl_xor(p0, 16, 64);
            p0 += __shfl_xor(p0, 32, 64);
            p1 += __shfl_xor(p1, 16, 64);
            p1 += __shfl_xor(p1, 32, 64);

            if (q == 0) {
                const float w2v = (p & 1) ? w2o : w2e;   // same parity for both groups (+16)
                out[obase + it * 256]      = fa * p0 + fb * w2v;
                out[obase + it * 256 + 16] = fa * p1 + fb * w2v;
            }
        }
    }
}

extern "C" void kernel_launch(void* const* d_in, const int* in_sizes, int n_in,
                              void* d_out, int out_size, void* d_ws, size_t ws_size,
                              hipStream_t stream) {
    const float* lr  = (const float*)d_in[0];
    const float* hr  = (const float*)d_in[1];
    const float* w0g = (const float*)d_in[2];
    const float* w1g = (const float*)d_in[3];
    const float* w2g = (const float*)d_in[4];
    const float* w3g = (const float*)d_in[5];
    const float* w4g = (const float*)d_in[6];
    const float* w5g = (const float*)d_in[7];
    const float* t0g = (const float*)d_in[8];
    const float* t1g = (const float*)d_in[9];
    const float* t2g = (const float*)d_in[10];
    const float* fwg = (const float*)d_in[11];
    float* out = (float*)d_out;

    hipLaunchKernelGGL(cmfsm_kernel, dim3(NBLK), dim3(512), LDS_BYTES, stream,
                       lr, hr, w0g, w1g, w2g, w3g, w4g, w5g, t0g, t1g, t2g, fwg, out);
}

// Round 9
// 145.843 us; speedup vs baseline: 1.0274x; 1.0274x over previous
//
#include <hip/hip_runtime.h>

typedef short v8s __attribute__((ext_vector_type(8)));
typedef float v4f __attribute__((ext_vector_type(4)));
typedef unsigned v4u __attribute__((ext_vector_type(4)));

#define Wh   1024
#define Hh   512
#define HWh  (Wh * Hh)
#define Wlr  512
#define HWlr (Wlr * 256)
#define ITERS 4
#define NBLK  1024        // 1024 blocks x 8 waves x 4 iters x 16 px = 524288 px (half row/block)

// Weight fragment table: 53 frags x 512 shorts (W0:32, W1:16, W2:4, W3:1),
// lane-contiguous 16B frags. Pre-packed into d_ws by prep kernel.
// Main kernel keeps only frags 0..47 in LDS (layers 0+1); frags 48..52 are
// register-resident (loaded from d_ws) -> LDS = 48 KiB -> 3 blocks/CU robustly.
#define WFRAG_SHORTS (53 * 512)
#define LDS_FRAGS    48
#define LDS_BYTES    (LDS_FRAGS * 1024)   // 49152

__device__ __forceinline__ unsigned short f2bf(float f) {
    union { float f; unsigned u; } v; v.f = f;
    unsigned r = v.u + 0x7FFFu + ((v.u >> 16) & 1u);  // RNE (cold path only)
    return (unsigned short)(r >> 16);
}
// hot-path pack: single-instruction packed f32->bf16 (RNE; dst.lo=a, dst.hi=b)
__device__ __forceinline__ unsigned pk2(float a, float b) {
    unsigned r;
    asm("v_cvt_pk_bf16_f32 %0, %1, %2" : "=v"(r) : "v"(a), "v"(b));
    return r;
}
__device__ __forceinline__ float leaky(float x) { return fmaxf(x, 0.01f * x); }

// register relay: build next layer's B-fragment (K-slot ks*32+q*8+j) from this
// layer's two accumulators for mt=2ks ("e") and mt=2ks+1 ("o").
// K-permuted weights ensure slot (ks,j) <- channel (2ks+(j>>2))*16 + q*4 + (j&3).
__device__ __forceinline__ v8s relay(v4f e, v4f o) {
    v4u w;
    w[0] = pk2(leaky(e[0]), leaky(e[1]));
    w[1] = pk2(leaky(e[2]), leaky(e[3]));
    w[2] = pk2(leaky(o[0]), leaky(o[1]));
    w[3] = pk2(leaky(o[2]), leaky(o[3]));
    return __builtin_bit_cast(v8s, w);
}

// ---------- prep kernel: pack all 53 weight fragments into d_ws ----------
__global__ void prep_kernel(const float* __restrict__ w0g, const float* __restrict__ w1g,
                            const float* __restrict__ w2g, const float* __restrict__ w3g,
                            unsigned short* __restrict__ ws)
{
    const int f = blockIdx.x;     // 0..52
    const int l = threadIdx.x;    // 0..63
    const int pp = l & 15, qq = l >> 4;
    unsigned short* dst = ws + f * 512 + l * 8;

    if (f < 32) {                 // layer 0, identity K mapping
        int mt = f >> 2, ks = f & 3;
        const float* src = w0g + (mt * 16 + pp) * 128 + ks * 32 + qq * 8;
#pragma unroll
        for (int j = 0; j < 8; ++j) dst[j] = f2bf(src[j]);
    } else if (f < 48) {          // layer 1, K-permuted for register relay
        int g = f - 32, mt = g >> 2, ks = g & 3;
        const float* srcrow = w1g + (mt * 16 + pp) * 128;
#pragma unroll
        for (int j = 0; j < 8; ++j)
            dst[j] = f2bf(srcrow[ks * 32 + ((j >> 2) << 4) + qq * 4 + (j & 3)]);
    } else if (f < 52) {          // layer 2, K-permuted
        int g = f - 48, mt = g >> 1, ks = g & 1;
        const float* srcrow = w2g + (mt * 16 + pp) * 64;
#pragma unroll
        for (int j = 0; j < 8; ++j)
            dst[j] = f2bf(srcrow[ks * 32 + ((j >> 2) << 4) + qq * 4 + (j & 3)]);
    } else {                      // layer 3, K-permuted
        const float* srcrow = w3g + pp * 32;
#pragma unroll
        for (int j = 0; j < 8; ++j)
            dst[j] = f2bf(srcrow[((j >> 2) << 4) + qq * 4 + (j & 3)]);
    }
}

// 512-thread blocks, min-waves 2 (VGPR cap 256): the live set spills under any
// tighter bound — verified R1/R2 (1024-thr cap 128 -> 240MB scratch) and R4
// ((512,6) cap ~85 -> VGPR 40 + 59MB scratch). DO NOT TIGHTEN.
__global__ __launch_bounds__(512, 2)
void cmfsm_kernel(const float* __restrict__ lr, const float* __restrict__ hr,
                  const unsigned short* __restrict__ ws,
                  const float* __restrict__ w4g, const float* __restrict__ w5g,
                  const float* __restrict__ t0g, const float* __restrict__ t1g,
                  const float* __restrict__ t2g, const float* __restrict__ fwg,
                  float* __restrict__ out)
{
    extern __shared__ unsigned short smem[];
    unsigned short* wfrag = smem;                    // 48*512 shorts (layers 0+1)

    const int tid  = threadIdx.x;
    const int lane = tid & 63;
    const int wv   = tid >> 6;    // 0..7
    const int p    = lane & 15;   // MFMA n (pixel)
    const int q    = lane >> 4;   // MFMA k-quad

    // ---- cheap prologue: coalesced 48KB copy d_ws -> LDS (6 uint4/thread) ----
    {
        const uint4* src = (const uint4*)ws;
        uint4* dst = (uint4*)smem;
#pragma unroll
        for (int e = 0; e < 6; ++e) dst[tid + e * 512] = src[tid + e * 512];
    }

    // ---- fused linear layers 4+5: w45[r] = sum_j w5[j]*w4[j][4q+r] ----
    float w45[4];
#pragma unroll
    for (int r = 0; r < 4; ++r) {
        float s = 0.f;
#pragma unroll
        for (int j = 0; j < 8; ++j) s += w5g[j] * w4g[j * 16 + q * 4 + r];
        w45[r] = s;
    }

    // ---- block -> image mapping: row = blockIdx>>1, half-row = blockIdx&1 ----
    const int row  = blockIdx.x >> 1;
    const int half = blockIdx.x & 1;

    // ---- weights2: 4 parity values; row parity is block-uniform ----
    float w2e, w2o;   // value for even-x / odd-x pixels of this row
    {
        float tab[4];
#pragma unroll
        for (int yp = 0; yp < 2; ++yp)
#pragma unroll
            for (int xp = 0; xp < 2; ++xp) {
                float i0 = xp ? 1.f : -1.f;
                float i1 = yp ? 1.f : -1.f;
                float i2 = 1.41421356237309505f;
                float h0[3], h1[2];
                for (int o = 0; o < 3; ++o)
                    h0[o] = leaky(t0g[o*3+0]*i0 + t0g[o*3+1]*i1 + t0g[o*3+2]*i2);
                for (int o = 0; o < 2; ++o)
                    h1[o] = leaky(t1g[o*3+0]*h0[0] + t1g[o*3+1]*h0[1] + t1g[o*3+2]*h0[2]);
                tab[yp*2+xp] = t2g[0]*h1[0] + t2g[1]*h1[1];
            }
        const int yp = row & 1;
        w2e = yp ? tab[2] : tab[0];
        w2o = yp ? tab[3] : tab[1];
    }
    const float fa = fabsf(fwg[0]);
    const float fb = fabsf(fwg[1]);

    // ---- serial-tail A-fragments (layers 2+3) straight from d_ws (L2-hit) ----
    const v8s a2w[4] = {
        *(const v8s*)(ws + 48 * 512 + lane * 8), *(const v8s*)(ws + 49 * 512 + lane * 8),
        *(const v8s*)(ws + 50 * 512 + lane * 8), *(const v8s*)(ws + 51 * 512 + lane * 8)
    };
    const v8s a3 = *(const v8s*)(ws + 52 * 512 + lane * 8);

    __syncthreads();   // wfrag ready; everything after is wave-private

    const unsigned short* WL = wfrag + lane * 8;     // A-frag read base

    // ---- per-lane per-channel global pointers: lane (q,p) owns ch = q*8+j ----
    // hr base = row*Wh + half*512 + wv*16 + p, per-iter imm +128 floats (512B)
    // lr row = row>>1 (block-constant): base = (row>>1)*Wlr + half*256 + wv*8 + (p>>1), +64/iter
    const float* hrp[8];
    const float* lrp[8];
    {
        const int hbase = row * Wh + half * 512 + wv * 16 + p;
        const int lbase = (row >> 1) * Wlr + half * 256 + wv * 8 + (p >> 1);
#pragma unroll
        for (int j = 0; j < 8; ++j) {
            hrp[j] = hr + (size_t)(q * 8 + j) * HWh  + hbase;
            lrp[j] = lr + (size_t)(q * 8 + j) * HWlr + lbase;
        }
    }

    // output column base for this wave (q==0 lanes store)
    const int obase = row * Wh + half * 512 + wv * 16 + p;

    // ---- software pipeline: preload iteration 0's staging values ----
    float h[8], l[8];
#pragma unroll
    for (int j = 0; j < 8; ++j) { h[j] = hrp[j][0]; l[j] = lrp[j][0]; }

#pragma unroll
    for (int it = 0; it < ITERS; ++it) {
        // ---- layer-0 B fragments in registers ----
        //   ks0 = lr_up, ks1 = hr, ks2 = lr*hr, ks3 = (lr-hr)^2
        v4u bf0, bf1, bf2, bf3;
#pragma unroll
        for (int u = 0; u < 4; ++u) {
            float l0 = l[2*u], l1 = l[2*u+1];
            float h0 = h[2*u], h1 = h[2*u+1];
            bf0[u] = pk2(l0, l1);
            bf1[u] = pk2(h0, h1);
            bf2[u] = pk2(l0 * h0, l1 * h1);
            float d0 = l0 - h0, d1 = l1 - h1;
            bf3[u] = pk2(d0 * d0, d1 * d1);
        }
        v8s b0 = __builtin_bit_cast(v8s, bf0);
        v8s b1 = __builtin_bit_cast(v8s, bf1);
        v8s b2 = __builtin_bit_cast(v8s, bf2);
        v8s b3 = __builtin_bit_cast(v8s, bf3);

        // ---- prefetch next iteration (all-immediate addressing, it static) ----
        if (it + 1 < ITERS) {
            const int ho = (it + 1) * 128;   // hr: +128 floats/iter (imm 512B steps)
            const int lo = (it + 1) * 64;    // lr: +64 floats/iter  (imm 256B steps)
#pragma unroll
            for (int j = 0; j < 8; ++j) {
                h[j] = hrp[j][ho];
                l[j] = lrp[j][lo];
            }
        }

        // ---- layer 0: 128 -> 128, pair-wise relay (2 accumulators live) ----
        v8s c1[4];
#pragma unroll
        for (int ksp = 0; ksp < 4; ++ksp) {
            v4f ae = (v4f){0.f, 0.f, 0.f, 0.f};
            v4f ao = (v4f){0.f, 0.f, 0.f, 0.f};
#pragma unroll
            for (int ks = 0; ks < 4; ++ks) {
                v8s b = (ks == 0) ? b0 : (ks == 1) ? b1 : (ks == 2) ? b2 : b3;
                v8s we = *(const v8s*)(WL + ((2 * ksp)     * 4 + ks) * 512);
                v8s wo = *(const v8s*)(WL + ((2 * ksp + 1) * 4 + ks) * 512);
                ae = __builtin_amdgcn_mfma_f32_16x16x32_bf16(we, b, ae, 0, 0, 0);
                ao = __builtin_amdgcn_mfma_f32_16x16x32_bf16(wo, b, ao, 0, 0, 0);
            }
            c1[ksp] = relay(ae, ao);
        }

        // ---- layer 1: 128 -> 64, pair-wise ----
        v8s c2[2];
#pragma unroll
        for (int ksp = 0; ksp < 2; ++ksp) {
            v4f ae = (v4f){0.f, 0.f, 0.f, 0.f};
            v4f ao = (v4f){0.f, 0.f, 0.f, 0.f};
#pragma unroll
            for (int ks = 0; ks < 4; ++ks) {
                v8s we = *(const v8s*)(WL + (32 + (2 * ksp)     * 4 + ks) * 512);
                v8s wo = *(const v8s*)(WL + (32 + (2 * ksp + 1) * 4 + ks) * 512);
                ae = __builtin_amdgcn_mfma_f32_16x16x32_bf16(we, c1[ks], ae, 0, 0, 0);
                ao = __builtin_amdgcn_mfma_f32_16x16x32_bf16(wo, c1[ks], ao, 0, 0, 0);
            }
            c2[ksp] = relay(ae, ao);
        }

        // ---- layer 2: 64 -> 32 (single pair, A-frags in registers) ----
        v8s c3;
        {
            v4f ae = (v4f){0.f, 0.f, 0.f, 0.f};
            v4f ao = (v4f){0.f, 0.f, 0.f, 0.f};
#pragma unroll
            for (int ks = 0; ks < 2; ++ks) {
                ae = __builtin_amdgcn_mfma_f32_16x16x32_bf16(a2w[ks],     c2[ks], ae, 0, 0, 0);
                ao = __builtin_amdgcn_mfma_f32_16x16x32_bf16(a2w[2 + ks], c2[ks], ao, 0, 0, 0);
            }
            c3 = relay(ae, ao);
        }

        // ---- layer 3: 32 -> 16, fused 16->8->1, fuse with weights2 ----
        {
            v4f acc3 = __builtin_amdgcn_mfma_f32_16x16x32_bf16(a3, c3, (v4f){0.f, 0.f, 0.f, 0.f}, 0, 0, 0);

            float part = 0.f;
#pragma unroll
            for (int r = 0; r < 4; ++r) part += w45[r] * leaky(acc3[r]);
            part += __shfl_xor(part, 16, 64);
            part += __shfl_xor(part, 32, 64);

            if (q == 0) {
                const float w2v = (p & 1) ? w2o : w2e;
                out[obase + it * 128] = fa * part + fb * w2v;
            }
        }
    }
}

extern "C" void kernel_launch(void* const* d_in, const int* in_sizes, int n_in,
                              void* d_out, int out_size, void* d_ws, size_t ws_size,
                              hipStream_t stream) {
    const float* lr  = (const float*)d_in[0];
    const float* hr  = (const float*)d_in[1];
    const float* w0g = (const float*)d_in[2];
    const float* w1g = (const float*)d_in[3];
    const float* w2g = (const float*)d_in[4];
    const float* w3g = (const float*)d_in[5];
    const float* w4g = (const float*)d_in[6];
    const float* w5g = (const float*)d_in[7];
    const float* t0g = (const float*)d_in[8];
    const float* t1g = (const float*)d_in[9];
    const float* t2g = (const float*)d_in[10];
    const float* fwg = (const float*)d_in[11];
    float* out = (float*)d_out;
    unsigned short* ws = (unsigned short*)d_ws;   // needs 53*512*2 = 54272 B

    hipLaunchKernelGGL(prep_kernel, dim3(53), dim3(64), 0, stream,
                       w0g, w1g, w2g, w3g, ws);
    hipLaunchKernelGGL(cmfsm_kernel, dim3(NBLK), dim3(512), LDS_BYTES, stream,
                       lr, hr, ws, w4g, w5g, t0g, t1g, t2g, fwg, out);
}

// Round 10
// 144.651 us; speedup vs baseline: 1.0358x; 1.0082x over previous
//
#include <hip/hip_runtime.h>

typedef short v8s __attribute__((ext_vector_type(8)));
typedef float v4f __attribute__((ext_vector_type(4)));
typedef unsigned v4u __attribute__((ext_vector_type(4)));

#define Wh   1024
#define Hh   512
#define HWh  (Wh * Hh)
#define Wlr  512
#define HWlr (Wlr * 256)
#define ITERS 4
#define NBLK  512         // 512 blocks x 16 waves x 4 iters x 16 px = 524288 px (1 row/block)

// Weight fragment table: 53 frags x 512 shorts (W0:32, W1:16, W2:4, W3:1),
// lane-contiguous 16B frags. Pre-packed into d_ws by prep kernel.
// Main kernel keeps frags 0..47 in LDS (layers 0+1); frags 48..52 are
// register-resident. LDS = 48 KiB -> 2 x 1024-thr blocks/CU (96 KiB).
#define WFRAG_SHORTS (53 * 512)
#define LDS_FRAGS    48
#define LDS_BYTES    (LDS_FRAGS * 1024)   // 49152

__device__ __forceinline__ unsigned short f2bf(float f) {
    union { float f; unsigned u; } v; v.f = f;
    unsigned r = v.u + 0x7FFFu + ((v.u >> 16) & 1u);  // RNE (prep kernel only)
    return (unsigned short)(r >> 16);
}
// hot-path pack: single-instruction packed f32->bf16 (RNE; dst.lo=a, dst.hi=b)
__device__ __forceinline__ unsigned pk2(float a, float b) {
    unsigned r;
    asm("v_cvt_pk_bf16_f32 %0, %1, %2" : "=v"(r) : "v"(a), "v"(b));
    return r;
}
__device__ __forceinline__ float leaky(float x) { return fmaxf(x, 0.01f * x); }

// register relay: build next layer's B-fragment (K-slot ks*32+q*8+j) from this
// layer's two accumulators for mt=2ks ("e") and mt=2ks+1 ("o").
// K-permuted weights ensure slot (ks,j) <- channel (2ks+(j>>2))*16 + q*4 + (j&3).
__device__ __forceinline__ v8s relay(v4f e, v4f o) {
    v4u w;
    w[0] = pk2(leaky(e[0]), leaky(e[1]));
    w[1] = pk2(leaky(e[2]), leaky(e[3]));
    w[2] = pk2(leaky(o[0]), leaky(o[1]));
    w[3] = pk2(leaky(o[2]), leaky(o[3]));
    return __builtin_bit_cast(v8s, w);
}

// ---------- prep kernel: pack all 53 weight fragments into d_ws ----------
__global__ void prep_kernel(const float* __restrict__ w0g, const float* __restrict__ w1g,
                            const float* __restrict__ w2g, const float* __restrict__ w3g,
                            unsigned short* __restrict__ ws)
{
    const int f = blockIdx.x;     // 0..52
    const int l = threadIdx.x;    // 0..63
    const int pp = l & 15, qq = l >> 4;
    unsigned short* dst = ws + f * 512 + l * 8;

    if (f < 32) {                 // layer 0, identity K mapping
        int mt = f >> 2, ks = f & 3;
        const float* src = w0g + (mt * 16 + pp) * 128 + ks * 32 + qq * 8;
#pragma unroll
        for (int j = 0; j < 8; ++j) dst[j] = f2bf(src[j]);
    } else if (f < 48) {          // layer 1, K-permuted for register relay
        int g = f - 32, mt = g >> 2, ks = g & 3;
        const float* srcrow = w1g + (mt * 16 + pp) * 128;
#pragma unroll
        for (int j = 0; j < 8; ++j)
            dst[j] = f2bf(srcrow[ks * 32 + ((j >> 2) << 4) + qq * 4 + (j & 3)]);
    } else if (f < 52) {          // layer 2, K-permuted
        int g = f - 48, mt = g >> 1, ks = g & 1;
        const float* srcrow = w2g + (mt * 16 + pp) * 64;
#pragma unroll
        for (int j = 0; j < 8; ++j)
            dst[j] = f2bf(srcrow[ks * 32 + ((j >> 2) << 4) + qq * 4 + (j & 3)]);
    } else {                      // layer 3, K-permuted
        const float* srcrow = w3g + pp * 32;
#pragma unroll
        for (int j = 0; j < 8; ++j)
            dst[j] = f2bf(srcrow[((j >> 2) << 4) + qq * 4 + (j & 3)]);
    }
}

// 1024-thread blocks (16 waves), cap 128 VGPR via (1024,4): the pair-wise relay
// body compiles to ~64 VGPR (R6/R8 measured), so no spill risk — the R1/R2
// 1024-thr spills were the ~140-reg relay-all-at-once variant. If VGPR <= 64,
// HW co-schedules 2 blocks/CU = 32 waves/CU (2x every prior config's ceiling).
__global__ __launch_bounds__(1024, 4)
void cmfsm_kernel(const float* __restrict__ lr, const float* __restrict__ hr,
                  const unsigned short* __restrict__ ws,
                  const float* __restrict__ w4g, const float* __restrict__ w5g,
                  const float* __restrict__ t0g, const float* __restrict__ t1g,
                  const float* __restrict__ t2g, const float* __restrict__ fwg,
                  float* __restrict__ out)
{
    extern __shared__ unsigned short smem[];
    unsigned short* wfrag = smem;                    // 48*512 shorts (layers 0+1)

    const int tid  = threadIdx.x;
    const int lane = tid & 63;
    const int wv   = tid >> 6;    // 0..15
    const int p    = lane & 15;   // MFMA n (pixel)
    const int q    = lane >> 4;   // MFMA k-quad

    // ---- cheap prologue: coalesced 48KB copy d_ws -> LDS (3 uint4/thread) ----
    {
        const uint4* src = (const uint4*)ws;
        uint4* dst = (uint4*)smem;
#pragma unroll
        for (int e = 0; e < 3; ++e) dst[tid + e * 1024] = src[tid + e * 1024];
    }

    // ---- fused linear layers 4+5: w45[r] = sum_j w5[j]*w4[j][4q+r] ----
    float w45[4];
#pragma unroll
    for (int r = 0; r < 4; ++r) {
        float s = 0.f;
#pragma unroll
        for (int j = 0; j < 8; ++j) s += w5g[j] * w4g[j * 16 + q * 4 + r];
        w45[r] = s;
    }

    // ---- block -> image mapping: one full row per block ----
    const int row = blockIdx.x;

    // ---- weights2: 4 parity values; row parity is block-uniform ----
    float w2e, w2o;   // value for even-x / odd-x pixels of this row
    {
        float tab[4];
#pragma unroll
        for (int yp = 0; yp < 2; ++yp)
#pragma unroll
            for (int xp = 0; xp < 2; ++xp) {
                float i0 = xp ? 1.f : -1.f;
                float i1 = yp ? 1.f : -1.f;
                float i2 = 1.41421356237309505f;
                float h0[3], h1[2];
                for (int o = 0; o < 3; ++o)
                    h0[o] = leaky(t0g[o*3+0]*i0 + t0g[o*3+1]*i1 + t0g[o*3+2]*i2);
                for (int o = 0; o < 2; ++o)
                    h1[o] = leaky(t1g[o*3+0]*h0[0] + t1g[o*3+1]*h0[1] + t1g[o*3+2]*h0[2]);
                tab[yp*2+xp] = t2g[0]*h1[0] + t2g[1]*h1[1];
            }
        const int yp = row & 1;
        w2e = yp ? tab[2] : tab[0];
        w2o = yp ? tab[3] : tab[1];
    }
    const float fa = fabsf(fwg[0]);
    const float fb = fabsf(fwg[1]);

    // ---- serial-tail A-fragments (layers 2+3) straight from d_ws (L2-hit) ----
    const v8s a2w[4] = {
        *(const v8s*)(ws + 48 * 512 + lane * 8), *(const v8s*)(ws + 49 * 512 + lane * 8),
        *(const v8s*)(ws + 50 * 512 + lane * 8), *(const v8s*)(ws + 51 * 512 + lane * 8)
    };
    const v8s a3 = *(const v8s*)(ws + 52 * 512 + lane * 8);

    __syncthreads();   // wfrag ready; everything after is wave-private

    const unsigned short* WL = wfrag + lane * 8;     // A-frag read base

    // ---- per-lane per-channel global pointers: lane (q,p) owns ch = q*8+j ----
    // hr base = row*Wh + wv*16 + p, per-iter imm +256 floats (1024B)
    // lr row = row>>1 (block-constant): base = (row>>1)*Wlr + wv*8 + (p>>1), +128/iter (512B)
    const float* hrp[8];
    const float* lrp[8];
    {
        const int hbase = row * Wh + wv * 16 + p;
        const int lbase = (row >> 1) * Wlr + wv * 8 + (p >> 1);
#pragma unroll
        for (int j = 0; j < 8; ++j) {
            hrp[j] = hr + (size_t)(q * 8 + j) * HWh  + hbase;
            lrp[j] = lr + (size_t)(q * 8 + j) * HWlr + lbase;
        }
    }

    // output column base for this wave (q==0 lanes store)
    const int obase = row * Wh + wv * 16 + p;

    // ---- software pipeline: preload iteration 0's staging values ----
    float h[8], l[8];
#pragma unroll
    for (int j = 0; j < 8; ++j) { h[j] = hrp[j][0]; l[j] = lrp[j][0]; }

#pragma unroll
    for (int it = 0; it < ITERS; ++it) {
        // ---- layer-0 B fragments in registers ----
        //   ks0 = lr_up, ks1 = hr, ks2 = lr*hr, ks3 = (lr-hr)^2
        v4u bf0, bf1, bf2, bf3;
#pragma unroll
        for (int u = 0; u < 4; ++u) {
            float l0 = l[2*u], l1 = l[2*u+1];
            float h0 = h[2*u], h1 = h[2*u+1];
            bf0[u] = pk2(l0, l1);
            bf1[u] = pk2(h0, h1);
            bf2[u] = pk2(l0 * h0, l1 * h1);
            float d0 = l0 - h0, d1 = l1 - h1;
            bf3[u] = pk2(d0 * d0, d1 * d1);
        }
        v8s b0 = __builtin_bit_cast(v8s, bf0);
        v8s b1 = __builtin_bit_cast(v8s, bf1);
        v8s b2 = __builtin_bit_cast(v8s, bf2);
        v8s b3 = __builtin_bit_cast(v8s, bf3);

        // ---- prefetch next iteration (all-immediate addressing, it static) ----
        if (it + 1 < ITERS) {
            const int ho = (it + 1) * 256;   // hr: +256 floats/iter (imm 1024B steps)
            const int lo = (it + 1) * 128;   // lr: +128 floats/iter (imm 512B steps)
#pragma unroll
            for (int j = 0; j < 8; ++j) {
                h[j] = hrp[j][ho];
                l[j] = lrp[j][lo];
            }
        }

        // ---- layer 0: 128 -> 128, pair-wise relay (2 accumulators live) ----
        v8s c1[4];
#pragma unroll
        for (int ksp = 0; ksp < 4; ++ksp) {
            v4f ae = (v4f){0.f, 0.f, 0.f, 0.f};
            v4f ao = (v4f){0.f, 0.f, 0.f, 0.f};
#pragma unroll
            for (int ks = 0; ks < 4; ++ks) {
                v8s b = (ks == 0) ? b0 : (ks == 1) ? b1 : (ks == 2) ? b2 : b3;
                v8s we = *(const v8s*)(WL + ((2 * ksp)     * 4 + ks) * 512);
                v8s wo = *(const v8s*)(WL + ((2 * ksp + 1) * 4 + ks) * 512);
                ae = __builtin_amdgcn_mfma_f32_16x16x32_bf16(we, b, ae, 0, 0, 0);
                ao = __builtin_amdgcn_mfma_f32_16x16x32_bf16(wo, b, ao, 0, 0, 0);
            }
            c1[ksp] = relay(ae, ao);
        }

        // ---- layer 1: 128 -> 64, pair-wise ----
        v8s c2[2];
#pragma unroll
        for (int ksp = 0; ksp < 2; ++ksp) {
            v4f ae = (v4f){0.f, 0.f, 0.f, 0.f};
            v4f ao = (v4f){0.f, 0.f, 0.f, 0.f};
#pragma unroll
            for (int ks = 0; ks < 4; ++ks) {
                v8s we = *(const v8s*)(WL + (32 + (2 * ksp)     * 4 + ks) * 512);
                v8s wo = *(const v8s*)(WL + (32 + (2 * ksp + 1) * 4 + ks) * 512);
                ae = __builtin_amdgcn_mfma_f32_16x16x32_bf16(we, c1[ks], ae, 0, 0, 0);
                ao = __builtin_amdgcn_mfma_f32_16x16x32_bf16(wo, c1[ks], ao, 0, 0, 0);
            }
            c2[ksp] = relay(ae, ao);
        }

        // ---- layer 2: 64 -> 32 (single pair, A-frags in registers) ----
        v8s c3;
        {
            v4f ae = (v4f){0.f, 0.f, 0.f, 0.f};
            v4f ao = (v4f){0.f, 0.f, 0.f, 0.f};
#pragma unroll
            for (int ks = 0; ks < 2; ++ks) {
                ae = __builtin_amdgcn_mfma_f32_16x16x32_bf16(a2w[ks],     c2[ks], ae, 0, 0, 0);
                ao = __builtin_amdgcn_mfma_f32_16x16x32_bf16(a2w[2 + ks], c2[ks], ao, 0, 0, 0);
            }
            c3 = relay(ae, ao);
        }

        // ---- layer 3: 32 -> 16, fused 16->8->1, fuse with weights2 ----
        {
            v4f acc3 = __builtin_amdgcn_mfma_f32_16x16x32_bf16(a3, c3, (v4f){0.f, 0.f, 0.f, 0.f}, 0, 0, 0);

            float part = 0.f;
#pragma unroll
            for (int r = 0; r < 4; ++r) part += w45[r] * leaky(acc3[r]);
            part += __shfl_xor(part, 16, 64);
            part += __shfl_xor(part, 32, 64);

            if (q == 0) {
                const float w2v = (p & 1) ? w2o : w2e;
                out[obase + it * 256] = fa * part + fb * w2v;
            }
        }
    }
}

extern "C" void kernel_launch(void* const* d_in, const int* in_sizes, int n_in,
                              void* d_out, int out_size, void* d_ws, size_t ws_size,
                              hipStream_t stream) {
    const float* lr  = (const float*)d_in[0];
    const float* hr  = (const float*)d_in[1];
    const float* w0g = (const float*)d_in[2];
    const float* w1g = (const float*)d_in[3];
    const float* w2g = (const float*)d_in[4];
    const float* w3g = (const float*)d_in[5];
    const float* w4g = (const float*)d_in[6];
    const float* w5g = (const float*)d_in[7];
    const float* t0g = (const float*)d_in[8];
    const float* t1g = (const float*)d_in[9];
    const float* t2g = (const float*)d_in[10];
    const float* fwg = (const float*)d_in[11];
    float* out = (float*)d_out;
    unsigned short* ws = (unsigned short*)d_ws;   // needs 53*512*2 = 54272 B

    hipLaunchKernelGGL(prep_kernel, dim3(53), dim3(64), 0, stream,
                       w0g, w1g, w2g, w3g, ws);
    hipLaunchKernelGGL(cmfsm_kernel, dim3(NBLK), dim3(1024), LDS_BYTES, stream,
                       lr, hr, ws, w4g, w5g, t0g, t1g, t2g, fwg, out);
}